// Round 1
// baseline (51.759 us; speedup 1.0000x reference)
//
#include <hip/hip_runtime.h>
#include <math.h>

// Health_State_Analysis: B=16384 rows, S=2560 fp32 samples each -> 15 stats/row.
// One wave (64 lanes) per row; each lane holds a contiguous 40-elem segment in
// registers. fp64 for mean/var/outlier boundary (integer-valued output!),
// fp32 for higher moments and diff stats.

constexpr int S_LEN = 2560;
constexpr int PER   = 40;          // elements per lane (64 * 40 = 2560)

__global__ __launch_bounds__(256)
void health_stats_kernel(const float* __restrict__ in, float* __restrict__ out) {
    const int lane = threadIdx.x & 63;
    const int wave = threadIdx.x >> 6;
    const int row  = blockIdx.x * 4 + wave;

    const float* rp = in + (size_t)row * S_LEN + (size_t)lane * PER;

    // ---- pass 1: load into registers, accumulate sum / |sum| / max / min ----
    float xr[PER + 2];
    double sum = 0.0;
    float sabs = 0.0f;
    float vmax = -INFINITY, vmin = INFINITY;

#pragma unroll
    for (int k = 0; k < PER / 4; ++k) {
        float4 v = *reinterpret_cast<const float4*>(rp + 4 * k);
        xr[4 * k + 0] = v.x; xr[4 * k + 1] = v.y;
        xr[4 * k + 2] = v.z; xr[4 * k + 3] = v.w;
        sum += ((double)v.x + (double)v.y) + ((double)v.z + (double)v.w);
        sabs += (fabsf(v.x) + fabsf(v.y)) + (fabsf(v.z) + fabsf(v.w));
        vmax = fmaxf(vmax, fmaxf(fmaxf(v.x, v.y), fmaxf(v.z, v.w)));
        vmin = fminf(vmin, fminf(fminf(v.x, v.y), fminf(v.z, v.w)));
    }
    // neighbor lane's first two elements (for d1/d2/zcr at segment boundary)
    xr[PER]     = __shfl_down(xr[0], 1);
    xr[PER + 1] = __shfl_down(xr[1], 1);

    // ---- wave reduction of pass-1 stats ----
#pragma unroll
    for (int o = 32; o > 0; o >>= 1) {
        sum  += __shfl_xor(sum, o);
        sabs += __shfl_xor(sabs, o);
        vmax  = fmaxf(vmax, __shfl_xor(vmax, o));
        vmin  = fminf(vmin, __shfl_xor(vmin, o));
    }
    const double mean = sum * (1.0 / S_LEN);

    // ---- pass 2a: exact centered sum of squares (fp64) ----
    double sc2 = 0.0;
#pragma unroll
    for (int j = 0; j < PER; ++j) {
        double c = (double)xr[j] - mean;
        sc2 = fma(c, c, sc2);
    }
#pragma unroll
    for (int o = 32; o > 0; o >>= 1) sc2 += __shfl_xor(sc2, o);

    const double var  = sc2 * (1.0 / (S_LEN - 1));   // ddof=1
    const double stdv = sqrt(var);
    const double thr  = 3.0 * stdv;

    // ---- pass 2b: higher moments, outliers, zcr, Hjorth diffs ----
    float c3 = 0.f, c4 = 0.f, outl = 0.f, zc = 0.f;
    float s1 = 0.f, s1q = 0.f, s2 = 0.f, s2q = 0.f;
    const int base = lane * PER;

#pragma unroll
    for (int j = 0; j < PER; ++j) {
        float x0 = xr[j];
        double cd = (double)x0 - mean;
        float c  = (float)cd;
        float c2 = c * c;
        c3 = fmaf(c2, c, c3);
        c4 = fmaf(c2, c2, c4);
        if (fabs(cd) > thr) outl += 1.f;

        float x1 = xr[j + 1];   // j==39 -> neighbor's first element
        float x2 = xr[j + 2];   // j>=38 -> neighbor's first/second element

        if (base + j < S_LEN - 1) {         // d1 & zero-crossing valid
            float d1 = x1 - x0;
            s1 += d1;
            s1q = fmaf(d1, d1, s1q);
            float sg0 = (x0 > 0.f) ? 1.f : ((x0 < 0.f) ? -1.f : 0.f);
            float sg1 = (x1 > 0.f) ? 1.f : ((x1 < 0.f) ? -1.f : 0.f);
            if (sg0 != sg1) zc += 1.f;
        }
        if (base + j < S_LEN - 2) {         // d2 valid
            float d1a = x1 - x0;            // matches numpy diff rounding
            float d1b = x2 - x1;
            float d2  = d1b - d1a;
            s2 += d2;
            s2q = fmaf(d2, d2, s2q);
        }
    }

#pragma unroll
    for (int o = 32; o > 0; o >>= 1) {
        c3  += __shfl_xor(c3, o);
        c4  += __shfl_xor(c4, o);
        outl += __shfl_xor(outl, o);
        zc  += __shfl_xor(zc, o);
        s1  += __shfl_xor(s1, o);
        s1q += __shfl_xor(s1q, o);
        s2  += __shfl_xor(s2, o);
        s2q += __shfl_xor(s2q, o);
    }

    // ---- epilogue: lane 0 writes the 15 stats ----
    if (lane == 0) {
        const double rms    = sqrt(sc2 * (1.0 / S_LEN) + mean * mean);
        const double m3     = (double)c3 * (1.0 / S_LEN);
        const double m4     = (double)c4 * (1.0 / S_LEN);
        const double skew   = m3 / (var * stdv);          // std^3
        const double kurt   = m4 / (var * var);           // std^4
        const double sabs_d = (double)sabs;
        const float  amax   = fmaxf(fabsf(vmax), fabsf(vmin));
        const double shape   = rms * (double)S_LEN / sabs_d;
        const double impulse = (double)amax * (double)S_LEN / sabs_d;
        // var(d1, ddof=1), len 2559 ; var(d2, ddof=1), len 2558 (raw moments)
        const double var1 = ((double)s1q - (double)s1 * (double)s1 / (S_LEN - 1)) / (S_LEN - 2);
        const double var2 = ((double)s2q - (double)s2 * (double)s2 / (S_LEN - 2)) / (S_LEN - 3);

        float* o = out + (size_t)row * 15;
        o[0]  = (float)mean;
        o[1]  = vmax;
        o[2]  = vmin;
        o[3]  = vmax - vmin;
        o[4]  = (float)var;
        o[5]  = (float)rms;
        o[6]  = (float)skew;
        o[7]  = (float)kurt;
        o[8]  = (float)shape;
        o[9]  = (float)impulse;
        o[10] = outl;
        o[11] = zc / (2.0f * S_LEN);
        o[12] = (float)var;          // activity == var
        o[13] = (float)sqrt(var1 / var);
        o[14] = (float)sqrt(var2 / var1);
    }
}

extern "C" void kernel_launch(void* const* d_in, const int* in_sizes, int n_in,
                              void* d_out, int out_size, void* d_ws, size_t ws_size,
                              hipStream_t stream) {
    (void)in_sizes; (void)n_in; (void)d_ws; (void)ws_size; (void)out_size;
    const float* in = (const float*)d_in[0];
    float* out = (float*)d_out;
    // 16384 rows, 4 rows per 256-thread block (1 wave per row)
    health_stats_kernel<<<4096, 256, 0, stream>>>(in, out);
}

// Round 2
// 42.225 us; speedup vs baseline: 1.2258x; 1.2258x over previous
//
#include <hip/hip_runtime.h>
#include <math.h>

// Health_State_Analysis: B=16384 rows, S=2560 fp32 -> 15 stats/row.
// One wave per row, COALESCED interleaved layout: xr[4k+j] = x[k*256 + 4*lane + j].
// Every float4 load is a contiguous 1KB wave transaction.
// f64 only for mean/var accumulation tails; outlier compare done exactly in f32
// via round-down/round-up f32 images of the f64 decision boundaries.

constexpr int S_LEN = 2560;

__global__ __launch_bounds__(256)
void health_stats_kernel(const float* __restrict__ in, float* __restrict__ out) {
    const int lane = threadIdx.x & 63;
    const int wave = threadIdx.x >> 6;
    const int row  = blockIdx.x * 4 + wave;

    const float* rp = in + (size_t)row * S_LEN + lane * 4;

    float xr[40];
    double sum = 0.0, sq = 0.0;
    float sabs = 0.0f, vmax = -INFINITY, vmin = INFINITY;

    // ---- pass 1: coalesced load + raw sums (f32 8-elem partials -> f64) ----
#pragma unroll
    for (int k = 0; k < 10; k += 2) {
        float4 a = *reinterpret_cast<const float4*>(rp + k * 256);
        float4 b = *reinterpret_cast<const float4*>(rp + (k + 1) * 256);
        xr[4*k+0]=a.x; xr[4*k+1]=a.y; xr[4*k+2]=a.z; xr[4*k+3]=a.w;
        xr[4*k+4]=b.x; xr[4*k+5]=b.y; xr[4*k+6]=b.z; xr[4*k+7]=b.w;

        float s8 = ((a.x + a.y) + (a.z + a.w)) + ((b.x + b.y) + (b.z + b.w));
        float q8 = fmaf(a.x, a.x, fmaf(a.y, a.y, fmaf(a.z, a.z, a.w * a.w)))
                 + fmaf(b.x, b.x, fmaf(b.y, b.y, fmaf(b.z, b.z, b.w * b.w)));
        sum += (double)s8;
        sq  += (double)q8;

        sabs += ((fabsf(a.x) + fabsf(a.y)) + (fabsf(a.z) + fabsf(a.w)))
              + ((fabsf(b.x) + fabsf(b.y)) + (fabsf(b.z) + fabsf(b.w)));
        vmax = fmaxf(vmax, fmaxf(fmaxf(fmaxf(a.x, a.y), fmaxf(a.z, a.w)),
                                 fmaxf(fmaxf(b.x, b.y), fmaxf(b.z, b.w))));
        vmin = fminf(vmin, fminf(fminf(fminf(a.x, a.y), fminf(a.z, a.w)),
                                 fminf(fminf(b.x, b.y), fminf(b.z, b.w))));
    }

#pragma unroll
    for (int o = 32; o > 0; o >>= 1) {
        sum  += __shfl_xor(sum, o);
        sq   += __shfl_xor(sq, o);
        sabs += __shfl_xor(sabs, o);
        vmax  = fmaxf(vmax, __shfl_xor(vmax, o));
        vmin  = fminf(vmin, __shfl_xor(vmin, o));
    }

    const double mean = sum * (1.0 / S_LEN);
    const double var  = (sq - sum * mean) * (1.0 / (S_LEN - 1));  // no cancellation: n*mean^2 ~ 1 << sq ~ 2560
    const double stdv = sqrt(var);
    const double thr  = 3.0 * stdv;

    // exact f32 decision boundaries: for f32 x, (x > bhi_f64) <=> (x > RD_f32(bhi));
    // (x < blo_f64) <=> (x < RU_f32(blo)). Both adjustments are a bits-1 step toward 0.
    const double bhi = mean + thr, blo = mean - thr;
    float bhi_f = (float)bhi;
    if ((double)bhi_f > bhi) bhi_f = __int_as_float(__float_as_int(bhi_f) - 1);  // bhi>0: toward -inf
    float blo_f = (float)blo;
    if ((double)blo_f < blo) blo_f = __int_as_float(__float_as_int(blo_f) - 1);  // blo<0: toward +inf

    // ---- pass 2: central moments, outliers, zcr, Hjorth diffs ----
    const float mf = (float)mean;
    float c3s = 0.f, c4s = 0.f, s1q = 0.f, s2q = 0.f;
    int outc = 0, zcc = 0;

#pragma unroll
    for (int k = 0; k < 10; ++k) {
        const float x0 = xr[4*k+0], x1 = xr[4*k+1], x2v = xr[4*k+2], x3 = xr[4*k+3];
        // next two elements after this lane's chunk: lane<63 -> lane+1's chunk k;
        // lane 63 -> lane 0's chunk k+1 (push-value trick, single shfl each).
        const int kn = (k == 9) ? 0 : (k + 1);   // k=9 values are guarded off below
        float v0 = (lane == 0) ? xr[4*kn+0] : x0;
        float v1 = (lane == 0) ? xr[4*kn+1] : x1;
        const float n0 = __shfl(v0, (lane + 1) & 63);
        const float n1 = __shfl(v1, (lane + 1) & 63);

        // central moments (f32; tolerance 0.36 >> 1e-5 error)
        const float c0 = x0 - mf, c1 = x1 - mf, c2 = x2v - mf, c3 = x3 - mf;
        const float q0 = c0*c0, q1 = c1*c1, q2 = c2*c2, q3 = c3*c3;
        c3s = fmaf(q0, c0, fmaf(q1, c1, fmaf(q2, c2, fmaf(q3, c3, c3s))));
        c4s = fmaf(q0, q0, fmaf(q1, q1, fmaf(q2, q2, fmaf(q3, q3, c4s))));

        // outliers: exact strict compares, wave-total via ballot+popcount (SALU)
        outc += __popcll(__ballot(x0  > bhi_f || x0  < blo_f));
        outc += __popcll(__ballot(x1  > bhi_f || x1  < blo_f));
        outc += __popcll(__ballot(x2v > bhi_f || x2v < blo_f));
        outc += __popcll(__ballot(x3  > bhi_f || x3  < blo_f));

        // first/second differences
        const float d10 = x1 - x0, d11 = x2v - x1, d12 = x3 - x2v;
        const float d13 = n0 - x3,  d14 = n1 - n0;
        const float e0 = d11 - d10, e1 = d12 - d11, e2 = d13 - d12, e3 = d14 - d13;

        // zero crossings via sign-bit xor (exact-zero samples ~never; error << tol)
        const int b0 = __float_as_int(x0), b1 = __float_as_int(x1),
                  b2 = __float_as_int(x2v), b3 = __float_as_int(x3),
                  bn = __float_as_int(n0);

        if (k < 9) {
            s1q = fmaf(d10, d10, fmaf(d11, d11, fmaf(d12, d12, fmaf(d13, d13, s1q))));
            s2q = fmaf(e0, e0, fmaf(e1, e1, fmaf(e2, e2, fmaf(e3, e3, s2q))));
            zcc += __popcll(__ballot((b0 ^ b1) < 0));
            zcc += __popcll(__ballot((b1 ^ b2) < 0));
            zcc += __popcll(__ballot((b2 ^ b3) < 0));
            zcc += __popcll(__ballot((b3 ^ bn) < 0));
        } else {
            // only lane 63's tail (elements 2559 / d2 at 2558,2559) falls off the end
            const bool ok = lane < 63;
            s1q = fmaf(d10, d10, fmaf(d11, d11, fmaf(d12, d12, s1q)));
            s1q += ok ? d13 * d13 : 0.f;
            s2q = fmaf(e0, e0, fmaf(e1, e1, s2q));
            s2q += ok ? e2 * e2 : 0.f;
            s2q += ok ? e3 * e3 : 0.f;
            zcc += __popcll(__ballot((b0 ^ b1) < 0));
            zcc += __popcll(__ballot((b1 ^ b2) < 0));
            zcc += __popcll(__ballot((b2 ^ b3) < 0));
            zcc += __popcll(__ballot(((b3 ^ bn) < 0) && ok));
        }
    }

#pragma unroll
    for (int o = 32; o > 0; o >>= 1) {
        c3s += __shfl_xor(c3s, o);
        c4s += __shfl_xor(c4s, o);
        s1q += __shfl_xor(s1q, o);
        s2q += __shfl_xor(s2q, o);
    }

    // row endpoints for telescoped sum(d1), sum(d2)
    const float e0f = __shfl(xr[0], 0);    // x[0]
    const float e1f = __shfl(xr[1], 0);    // x[1]
    const float f2f = __shfl(xr[38], 63);  // x[2558]
    const float f3f = __shfl(xr[39], 63);  // x[2559]

    if (lane == 0) {
        const double rms  = sqrt(sq * (1.0 / S_LEN));
        const double m3   = (double)c3s * (1.0 / S_LEN);
        const double m4   = (double)c4s * (1.0 / S_LEN);
        const double skew = m3 / (var * stdv);
        const double kurt = m4 / (var * var);
        const float  amax = fmaxf(fabsf(vmax), fabsf(vmin));
        const double shape   = rms * (double)S_LEN / (double)sabs;
        const double impulse = (double)amax * (double)S_LEN / (double)sabs;
        const double s1 = (double)f3f - (double)e0f;                                  // telescoped sum(d1)
        const double s2 = ((double)f3f - (double)f2f) - ((double)e1f - (double)e0f);  // telescoped sum(d2)
        const double var1 = ((double)s1q - s1 * s1 * (1.0 / (S_LEN - 1))) * (1.0 / (S_LEN - 2));
        const double var2 = ((double)s2q - s2 * s2 * (1.0 / (S_LEN - 2))) * (1.0 / (S_LEN - 3));

        float* o = out + (size_t)row * 15;
        o[0]  = (float)mean;
        o[1]  = vmax;
        o[2]  = vmin;
        o[3]  = vmax - vmin;
        o[4]  = (float)var;
        o[5]  = (float)rms;
        o[6]  = (float)skew;
        o[7]  = (float)kurt;
        o[8]  = (float)shape;
        o[9]  = (float)impulse;
        o[10] = (float)outc;
        o[11] = (float)zcc * (1.0f / (2.0f * S_LEN));
        o[12] = (float)var;
        o[13] = (float)sqrt(var1 / var);
        o[14] = (float)sqrt(var2 / var1);
    }
}

extern "C" void kernel_launch(void* const* d_in, const int* in_sizes, int n_in,
                              void* d_out, int out_size, void* d_ws, size_t ws_size,
                              hipStream_t stream) {
    (void)in_sizes; (void)n_in; (void)d_ws; (void)ws_size; (void)out_size;
    const float* in = (const float*)d_in[0];
    float* out = (float*)d_out;
    health_stats_kernel<<<4096, 256, 0, stream>>>(in, out);
}

// Round 3
// 42.097 us; speedup vs baseline: 1.2295x; 1.0030x over previous
//
#include <hip/hip_runtime.h>
#include <math.h>

// Health_State_Analysis: B=16384 rows, S=2560 fp32 -> 15 stats/row.
// TWO waves per row (half-row each, 20 elems/lane), coalesced interleaved
// layout; cross-wave combine via small LDS struct. f32 8-elem partials -> f64
// for mean/var; outlier compare exact in f32 via rounded f64 boundaries.

constexpr int S_LEN = 2560;
constexpr int HALF  = 1280;

struct RowLds {
    double sum[2];
    double sq[2];
    float  sabs[2], vmax[2], vmin[2];
    float  nb0, nb1;            // x[1280], x[1281]  (neighbor for half0 tail)
    float  ep0, ep1, ep2, ep3;  // x[0], x[1], x[2558], x[2559] (telescope endpoints)
    float  c3s[2], c4s[2], s1q[2], s2q[2];
    float  outc[2], zcc[2];
};

__global__ __launch_bounds__(256)
void health_stats_kernel(const float* __restrict__ in, float* __restrict__ out) {
    __shared__ RowLds lds[2];

    const int lane = threadIdx.x & 63;
    const int wid  = threadIdx.x >> 6;   // 0..3
    const int hidx = wid & 1;            // which half of the row
    const int rsl  = wid >> 1;           // row slot within block
    const int row  = blockIdx.x * 2 + rsl;

    RowLds& L = lds[rsl];

    const float* rp = in + (size_t)row * S_LEN + hidx * HALF + lane * 4;

    // ---- pass 1: coalesced load + raw sums ----
    float xr[20];
    float s8a = 0.f, q8a = 0.f;          // chunk-pair f32 partials (8-elem, proven precision)
    double sum = 0.0, sq = 0.0;
    float sabs = 0.f, vmax = -INFINITY, vmin = INFINITY;

#pragma unroll
    for (int k = 0; k < 5; ++k) {
        float4 a = *reinterpret_cast<const float4*>(rp + k * 256);
        xr[4*k+0]=a.x; xr[4*k+1]=a.y; xr[4*k+2]=a.z; xr[4*k+3]=a.w;
        float s4 = (a.x + a.y) + (a.z + a.w);
        float q4 = fmaf(a.x,a.x, fmaf(a.y,a.y, fmaf(a.z,a.z, a.w*a.w)));
        if ((k & 1) == 0) { s8a = s4; q8a = q4; }
        else              { sum += (double)(s8a + s4); sq += (double)(q8a + q4); }
        if (k == 4)       { sum += (double)s4; sq += (double)q4; }
        sabs += (fabsf(a.x)+fabsf(a.y)) + (fabsf(a.z)+fabsf(a.w));
        vmax = fmaxf(vmax, fmaxf(fmaxf(a.x,a.y), fmaxf(a.z,a.w)));
        vmin = fminf(vmin, fminf(fminf(a.x,a.y), fminf(a.z,a.w)));
    }

#pragma unroll
    for (int o = 32; o > 0; o >>= 1) {
        sum  += __shfl_xor(sum, o);
        sq   += __shfl_xor(sq, o);
        sabs += __shfl_xor(sabs, o);
        vmax  = fmaxf(vmax, __shfl_xor(vmax, o));
        vmin  = fminf(vmin, __shfl_xor(vmin, o));
    }

    if (lane == 0) {
        L.sum[hidx] = sum;  L.sq[hidx] = sq;
        L.sabs[hidx] = sabs; L.vmax[hidx] = vmax; L.vmin[hidx] = vmin;
        if (hidx == 0) { L.ep0 = xr[0]; L.ep1 = xr[1]; }
        else           { L.nb0 = xr[0]; L.nb1 = xr[1]; }
    }
    if (lane == 63 && hidx == 1) { L.ep2 = xr[18]; L.ep3 = xr[19]; }

    __syncthreads();

    const double tsum = L.sum[0] + L.sum[1];
    const double tsq  = L.sq[0]  + L.sq[1];
    const double mean = tsum * (1.0 / S_LEN);
    const double var  = (tsq - tsum * mean) * (1.0 / (S_LEN - 1));  // n*mean^2 ~ 1 << tsq: no cancellation
    const double stdv = sqrt(var);
    const double thr  = 3.0 * stdv;

    // exact f32 decision boundaries (bhi>0, blo<0 always for this data):
    // (x > bhi_f64) <=> (x > RD_f32(bhi)); (x < blo_f64) <=> (x < RU_f32(blo)).
    const double bhi = mean + thr, blo = mean - thr;
    float bhi_f = (float)bhi;
    if ((double)bhi_f > bhi) bhi_f = __int_as_float(__float_as_int(bhi_f) - 1);  // toward -inf (bhi>0)
    float blo_f = (float)blo;
    if ((double)blo_f < blo) blo_f = __int_as_float(__float_as_int(blo_f) - 1);  // toward +inf (blo<0)

    const float nbv0 = L.nb0, nbv1 = L.nb1;
    const float mf = (float)mean;

    // ---- pass 2: central moments, outliers, zcr, Hjorth diffs ----
    float c3s = 0.f, c4s = 0.f, s1q = 0.f, s2q = 0.f;
    int outc = 0, zcc = 0;

#pragma unroll
    for (int k = 0; k < 5; ++k) {
        const float x0 = xr[4*k+0], x1 = xr[4*k+1], x2v = xr[4*k+2], x3 = xr[4*k+3];
        const int kn = (k == 4) ? 0 : (k + 1);
        float v0 = (lane == 0) ? xr[4*kn+0] : x0;
        float v1 = (lane == 0) ? xr[4*kn+1] : x1;
        float n0 = __shfl(v0, (lane + 1) & 63);
        float n1 = __shfl(v1, (lane + 1) & 63);
        if (k == 4 && lane == 63) { n0 = nbv0; n1 = nbv1; }  // half1 uses: guarded off below

        const float c0 = x0 - mf, c1 = x1 - mf, c2 = x2v - mf, c3 = x3 - mf;
        const float q0 = c0*c0, q1 = c1*c1, q2 = c2*c2, q3 = c3*c3;
        c3s = fmaf(q0, c0, fmaf(q1, c1, fmaf(q2, c2, fmaf(q3, c3, c3s))));
        c4s = fmaf(q0, q0, fmaf(q1, q1, fmaf(q2, q2, fmaf(q3, q3, c4s))));

        outc += __popcll(__ballot(x0  > bhi_f || x0  < blo_f));
        outc += __popcll(__ballot(x1  > bhi_f || x1  < blo_f));
        outc += __popcll(__ballot(x2v > bhi_f || x2v < blo_f));
        outc += __popcll(__ballot(x3  > bhi_f || x3  < blo_f));

        const float d10 = x1 - x0, d11 = x2v - x1, d12 = x3 - x2v;
        const float d13 = n0 - x3, d14 = n1 - n0;
        const float e0 = d11 - d10, e1 = d12 - d11, e2 = d13 - d12, e3 = d14 - d13;

        const int b0 = __float_as_int(x0), b1 = __float_as_int(x1),
                  b2 = __float_as_int(x2v), b3 = __float_as_int(x3),
                  bn = __float_as_int(n0);
        zcc += __popcll(__ballot((b0 ^ b1) < 0));
        zcc += __popcll(__ballot((b1 ^ b2) < 0));
        zcc += __popcll(__ballot((b2 ^ b3) < 0));

        if (k < 4) {
            s1q = fmaf(d10, d10, fmaf(d11, d11, fmaf(d12, d12, fmaf(d13, d13, s1q))));
            s2q = fmaf(e0, e0, fmaf(e1, e1, fmaf(e2, e2, fmaf(e3, e3, s2q))));
            zcc += __popcll(__ballot((b3 ^ bn) < 0));
        } else {
            // half0: everything valid (lane63 spliced from nb). half1: row tail guards.
            const bool ok = (hidx == 0) || (lane < 63);
            s1q = fmaf(d10, d10, fmaf(d11, d11, fmaf(d12, d12, s1q)));
            s1q += ok ? d13 * d13 : 0.f;
            s2q = fmaf(e0, e0, fmaf(e1, e1, s2q));
            s2q += ok ? e2 * e2 : 0.f;
            s2q += ok ? e3 * e3 : 0.f;
            zcc += __popcll(__ballot(((b3 ^ bn) < 0) && ok));
        }
    }

#pragma unroll
    for (int o = 32; o > 0; o >>= 1) {
        c3s += __shfl_xor(c3s, o);
        c4s += __shfl_xor(c4s, o);
        s1q += __shfl_xor(s1q, o);
        s2q += __shfl_xor(s2q, o);
    }

    if (lane == 0) {
        L.c3s[hidx] = c3s;  L.c4s[hidx] = c4s;
        L.s1q[hidx] = s1q;  L.s2q[hidx] = s2q;
        L.outc[hidx] = (float)outc;  L.zcc[hidx] = (float)zcc;
    }

    __syncthreads();

    if (hidx == 0 && lane == 0) {
        const float tabs = L.sabs[0] + L.sabs[1];
        const float tmax = fmaxf(L.vmax[0], L.vmax[1]);
        const float tmin = fminf(L.vmin[0], L.vmin[1]);
        const float c3t  = L.c3s[0] + L.c3s[1];
        const float c4t  = L.c4s[0] + L.c4s[1];
        const float s1qt = L.s1q[0] + L.s1q[1];
        const float s2qt = L.s2q[0] + L.s2q[1];
        const float outt = L.outc[0] + L.outc[1];
        const float zct  = L.zcc[0] + L.zcc[1];

        const double rms  = sqrt(tsq * (1.0 / S_LEN));
        const double m3   = (double)c3t * (1.0 / S_LEN);
        const double m4   = (double)c4t * (1.0 / S_LEN);
        const double skew = m3 / (var * stdv);
        const double kurt = m4 / (var * var);
        const float  amax = fmaxf(fabsf(tmax), fabsf(tmin));
        const double shape   = rms * (double)S_LEN / (double)tabs;
        const double impulse = (double)amax * (double)S_LEN / (double)tabs;
        const double s1 = (double)L.ep3 - (double)L.ep0;                                    // telescoped sum(d1)
        const double s2 = ((double)L.ep3 - (double)L.ep2) - ((double)L.ep1 - (double)L.ep0); // telescoped sum(d2)
        const double var1 = ((double)s1qt - s1 * s1 * (1.0 / (S_LEN - 1))) * (1.0 / (S_LEN - 2));
        const double var2 = ((double)s2qt - s2 * s2 * (1.0 / (S_LEN - 2))) * (1.0 / (S_LEN - 3));

        float* o = out + (size_t)row * 15;
        o[0]  = (float)mean;
        o[1]  = tmax;
        o[2]  = tmin;
        o[3]  = tmax - tmin;
        o[4]  = (float)var;
        o[5]  = (float)rms;
        o[6]  = (float)skew;
        o[7]  = (float)kurt;
        o[8]  = (float)shape;
        o[9]  = (float)impulse;
        o[10] = outt;
        o[11] = zct * (1.0f / (2.0f * S_LEN));
        o[12] = (float)var;
        o[13] = (float)sqrt(var1 / var);
        o[14] = (float)sqrt(var2 / var1);
    }
}

extern "C" void kernel_launch(void* const* d_in, const int* in_sizes, int n_in,
                              void* d_out, int out_size, void* d_ws, size_t ws_size,
                              hipStream_t stream) {
    (void)in_sizes; (void)n_in; (void)d_ws; (void)ws_size; (void)out_size;
    const float* in = (const float*)d_in[0];
    float* out = (float*)d_out;
    // 16384 rows, 2 rows per 256-thread block (2 waves per row)
    health_stats_kernel<<<8192, 256, 0, stream>>>(in, out);
}

// Round 4
// 39.896 us; speedup vs baseline: 1.2974x; 1.0552x over previous
//
#include <hip/hip_runtime.h>
#include <math.h>

// Health_State_Analysis: B=16384 rows, S=2560 fp32 -> 15 stats/row.
// k1: 2 waves/row, coalesced interleave, DPP wave reductions (no DS shuffles),
//     packed-f32 moments, sign-mask zcr, partials -> ws (SoA float4 chunks).
// k2: 16384 threads, all f64 finalization at full lane parallelism.

typedef float f32x2 __attribute__((ext_vector_type(2)));
typedef float f32x4 __attribute__((ext_vector_type(4)));

constexpr int S_LEN = 2560;
constexpr int NROWS = 16384;

// ---- DPP wave-64 reductions (rocPRIM pattern): total lands in lane 63 ----
#define DPP_ADD_F32(x, ctrl) do { \
    int t_ = __builtin_amdgcn_update_dpp(0, __float_as_int(x), ctrl, 0xf, 0xf, false); \
    x += __int_as_float(t_); } while (0)
#define DPP_MAX_F32(x, ctrl) do { \
    int t_ = __builtin_amdgcn_update_dpp(__float_as_int(x), __float_as_int(x), ctrl, 0xf, 0xf, false); \
    x = fmaxf(x, __int_as_float(t_)); } while (0)
#define DPP_MIN_F32(x, ctrl) do { \
    int t_ = __builtin_amdgcn_update_dpp(__float_as_int(x), __float_as_int(x), ctrl, 0xf, 0xf, false); \
    x = fminf(x, __int_as_float(t_)); } while (0)

__device__ __forceinline__ float wave_sum_f32(float x) {
    DPP_ADD_F32(x, 0x111); DPP_ADD_F32(x, 0x112); DPP_ADD_F32(x, 0x114);
    DPP_ADD_F32(x, 0x118); DPP_ADD_F32(x, 0x142); DPP_ADD_F32(x, 0x143);
    return x;  // lane 63
}
__device__ __forceinline__ float wave_max_f32(float x) {
    DPP_MAX_F32(x, 0x111); DPP_MAX_F32(x, 0x112); DPP_MAX_F32(x, 0x114);
    DPP_MAX_F32(x, 0x118); DPP_MAX_F32(x, 0x142); DPP_MAX_F32(x, 0x143);
    return x;
}
__device__ __forceinline__ float wave_min_f32(float x) {
    DPP_MIN_F32(x, 0x111); DPP_MIN_F32(x, 0x112); DPP_MIN_F32(x, 0x114);
    DPP_MIN_F32(x, 0x118); DPP_MIN_F32(x, 0x142); DPP_MIN_F32(x, 0x143);
    return x;
}
__device__ __forceinline__ double wave_sum_f64(double x) {
#define DPP_ADD_F64(ctrl) do { \
    long long b_ = __double_as_longlong(x); \
    int lo_ = __builtin_amdgcn_update_dpp(0, (int)(b_ & 0xffffffffLL), ctrl, 0xf, 0xf, false); \
    int hi_ = __builtin_amdgcn_update_dpp(0, (int)(b_ >> 32), ctrl, 0xf, 0xf, false); \
    x += __longlong_as_double(((long long)hi_ << 32) | (unsigned int)lo_); } while (0)
    DPP_ADD_F64(0x111); DPP_ADD_F64(0x112); DPP_ADD_F64(0x114);
    DPP_ADD_F64(0x118); DPP_ADD_F64(0x142); DPP_ADD_F64(0x143);
#undef DPP_ADD_F64
    return x;  // lane 63
}
__device__ __forceinline__ double readlane_f64(double x, int l) {
    long long b = __double_as_longlong(x);
    int lo = __builtin_amdgcn_readlane((int)(b & 0xffffffffLL), l);
    int hi = __builtin_amdgcn_readlane((int)(b >> 32), l);
    return __longlong_as_double(((long long)hi << 32) | (unsigned int)lo);
}

__global__ __launch_bounds__(256)
void health_pass1(const float* __restrict__ in, float* __restrict__ ws) {
    __shared__ double Lsum[4], Lsq[4];
    __shared__ float  Lnb[2][2];

    const int lane = threadIdx.x & 63;
    const int wid  = threadIdx.x >> 6;   // 0..3
    const int hidx = wid & 1;            // half of row
    const int rsl  = wid >> 1;           // row slot in block
    const int row  = blockIdx.x * 2 + rsl;

    const f32x4* rp = reinterpret_cast<const f32x4*>(in)
                    + (size_t)row * (S_LEN / 4) + hidx * (1280 / 4) + lane;

    // ---- pass 1: coalesced load + raw sums (packed f32 -> f64 per lane) ----
    f32x4 X[5];
#pragma unroll
    for (int k = 0; k < 5; ++k) X[k] = rp[k * 64];

    f32x2 sp = {0.f, 0.f}, qp = {0.f, 0.f};
    float sabs = 0.f, vmax = -INFINITY, vmin = INFINITY;
#pragma unroll
    for (int k = 0; k < 5; ++k) {
        f32x2 lo = __builtin_shufflevector(X[k], X[k], 0, 1);
        f32x2 hi = __builtin_shufflevector(X[k], X[k], 2, 3);
        sp += lo + hi;
        qp = __builtin_elementwise_fma(lo, lo, qp);
        qp = __builtin_elementwise_fma(hi, hi, qp);
        sabs += (fabsf(X[k][0]) + fabsf(X[k][1])) + (fabsf(X[k][2]) + fabsf(X[k][3]));
        vmax = fmaxf(vmax, fmaxf(fmaxf(X[k][0], X[k][1]), fmaxf(X[k][2], X[k][3])));
        vmin = fminf(vmin, fminf(fminf(X[k][0], X[k][1]), fminf(X[k][2], X[k][3])));
    }

    const double sum_l = (double)sp.x + (double)sp.y;
    const double sq_l  = (double)qp.x + (double)qp.y;
    const double sum_u = readlane_f64(wave_sum_f64(sum_l), 63);
    const double sq_u  = readlane_f64(wave_sum_f64(sq_l), 63);

    // exchange sums with partner wave (other half of row)
    if (lane == 0) {
        Lsum[wid] = sum_u;  Lsq[wid] = sq_u;
        if (hidx == 1) { Lnb[rsl][0] = X[0][0]; Lnb[rsl][1] = X[0][1]; }
    }
    __syncthreads();
    const double tsum = Lsum[rsl * 2] + Lsum[rsl * 2 + 1];
    const double tsq  = Lsq[rsl * 2]  + Lsq[rsl * 2 + 1];

    const double mean = tsum * (1.0 / S_LEN);
    const double var  = (tsq - tsum * mean) * (1.0 / (S_LEN - 1));
    const double stdv = sqrt(var);
    const double thr  = 3.0 * stdv;
    const double bhi = mean + thr, blo = mean - thr;
    float bhi_f = (float)bhi;
    if ((double)bhi_f > bhi) bhi_f = __int_as_float(__float_as_int(bhi_f) - 1);  // RD (bhi>0)
    float blo_f = (float)blo;
    if ((double)blo_f < blo) blo_f = __int_as_float(__float_as_int(blo_f) - 1);  // RU (blo<0)

    const float nbv0 = Lnb[rsl][0], nbv1 = Lnb[rsl][1];
    const float mf = (float)mean;
    const f32x2 nmf2 = {-mf, -mf};

    // ---- pass 2: moments (packed), outliers, zcr (sign masks), diffs ----
    f32x2 c3p = {0.f, 0.f}, c4p = {0.f, 0.f};
    float s1q = 0.f, s2q = 0.f;
    int outc = 0, zcc = 0;
    const unsigned long long tail_ok = (hidx == 0) ? ~0ULL : 0x7FFFFFFFFFFFFFFFULL;

#pragma unroll
    for (int k = 0; k < 5; ++k) {
        const float x0 = X[k][0], x1 = X[k][1], x2v = X[k][2], x3 = X[k][3];
        const int kn = (k == 4) ? 0 : (k + 1);
        float v0 = (lane == 0) ? X[kn][0] : x0;
        float v1 = (lane == 0) ? X[kn][1] : x1;
        float n0 = __shfl(v0, (lane + 1) & 63);
        float n1 = __shfl(v1, (lane + 1) & 63);
        if (k == 4 && lane == 63) { n0 = nbv0; n1 = nbv1; }  // half1: guarded below

        f32x2 lo = __builtin_shufflevector(X[k], X[k], 0, 1);
        f32x2 hi = __builtin_shufflevector(X[k], X[k], 2, 3);
        f32x2 cl = lo + nmf2, ch = hi + nmf2;
        f32x2 ql = cl * cl,  qh = ch * ch;
        c3p = __builtin_elementwise_fma(ql, cl, c3p);
        c3p = __builtin_elementwise_fma(qh, ch, c3p);
        c4p = __builtin_elementwise_fma(ql, ql, c4p);
        c4p = __builtin_elementwise_fma(qh, qh, c4p);

        outc += __popcll(__ballot(x0  > bhi_f || x0  < blo_f));
        outc += __popcll(__ballot(x1  > bhi_f || x1  < blo_f));
        outc += __popcll(__ballot(x2v > bhi_f || x2v < blo_f));
        outc += __popcll(__ballot(x3  > bhi_f || x3  < blo_f));

        const unsigned long long m0 = __ballot(x0  < 0.f);
        const unsigned long long m1 = __ballot(x1  < 0.f);
        const unsigned long long m2 = __ballot(x2v < 0.f);
        const unsigned long long m3 = __ballot(x3  < 0.f);
        const unsigned long long mn = __ballot(n0  < 0.f);
        zcc += __popcll(m0 ^ m1) + __popcll(m1 ^ m2) + __popcll(m2 ^ m3);
        zcc += __popcll((m3 ^ mn) & ((k == 4) ? tail_ok : ~0ULL));

        const float d10 = x1 - x0, d11 = x2v - x1, d12 = x3 - x2v;
        const float d13 = n0 - x3, d14 = n1 - n0;
        const float e0 = d11 - d10, e1 = d12 - d11, e2 = d13 - d12, e3 = d14 - d13;
        if (k < 4) {
            s1q = fmaf(d10, d10, fmaf(d11, d11, fmaf(d12, d12, fmaf(d13, d13, s1q))));
            s2q = fmaf(e0, e0, fmaf(e1, e1, fmaf(e2, e2, fmaf(e3, e3, s2q))));
        } else {
            const bool ok = (hidx == 0) || (lane < 63);
            s1q = fmaf(d10, d10, fmaf(d11, d11, fmaf(d12, d12, s1q)));
            s1q += ok ? d13 * d13 : 0.f;
            s2q = fmaf(e0, e0, fmaf(e1, e1, s2q));
            s2q += ok ? e2 * e2 : 0.f;
            s2q += ok ? e3 * e3 : 0.f;
        }
    }

    float sabs_t = wave_sum_f32(sabs);
    float c3_t   = wave_sum_f32(c3p.x + c3p.y);
    float c4_t   = wave_sum_f32(c4p.x + c4p.y);
    float s1q_t  = wave_sum_f32(s1q);
    float s2q_t  = wave_sum_f32(s2q);
    float vmax_t = wave_max_f32(vmax);
    float vmin_t = wave_min_f32(vmin);

    float ep_a, ep_b;   // half0: x[0],x[1];  half1: x[2558],x[2559]
    if (hidx == 0) {
        ep_a = __int_as_float(__builtin_amdgcn_readlane(__float_as_int(X[0][0]), 0));
        ep_b = __int_as_float(__builtin_amdgcn_readlane(__float_as_int(X[0][1]), 0));
    } else {
        ep_a = X[4][2];  ep_b = X[4][3];   // valid on lane 63 (the storing lane)
    }

    if (lane == 63) {
        double2* Wd = reinterpret_cast<double2*>(ws);
        f32x4*   Wf = reinterpret_cast<f32x4*>(ws);
        double2 dsum; dsum.x = sum_u; dsum.y = sq_u;
        Wd[(size_t)hidx * NROWS + row] = dsum;                       // chunks 0,1
        const size_t b = (size_t)(2 + hidx * 3) * NROWS + row;       // chunks 2..7
        Wf[b]             = f32x4{sabs_t, vmax_t, vmin_t, c3_t};
        Wf[b + NROWS]     = f32x4{c4_t, s1q_t, s2q_t, (float)outc};
        Wf[b + 2 * NROWS] = f32x4{(float)zcc, ep_a, ep_b, 0.f};
    }
}

__global__ __launch_bounds__(256)
void health_finalize(const float* __restrict__ ws, float* __restrict__ out) {
    const int row = blockIdx.x * 256 + threadIdx.x;
    const double2* Wd = reinterpret_cast<const double2*>(ws);
    const f32x4*   Wf = reinterpret_cast<const f32x4*>(ws);

    const double2 s0 = Wd[row], s1 = Wd[NROWS + row];
    const f32x4 a0 = Wf[2 * NROWS + row], a1 = Wf[3 * NROWS + row], a2 = Wf[4 * NROWS + row];
    const f32x4 b0 = Wf[5 * NROWS + row], b1 = Wf[6 * NROWS + row], b2 = Wf[7 * NROWS + row];

    const double tsum = s0.x + s1.x;
    const double tsq  = s0.y + s1.y;
    const double mean = tsum * (1.0 / S_LEN);
    const double var  = (tsq - tsum * mean) * (1.0 / (S_LEN - 1));
    const double stdv = sqrt(var);

    const float tabs = a0[0] + b0[0];
    const float tmax = fmaxf(a0[1], b0[1]);
    const float tmin = fminf(a0[2], b0[2]);
    const float c3t  = a0[3] + b0[3];
    const float c4t  = a1[0] + b1[0];
    const float s1qt = a1[1] + b1[1];
    const float s2qt = a1[2] + b1[2];
    const float outt = a1[3] + b1[3];
    const float zct  = a2[0] + b2[0];
    const float ep0 = a2[1], ep1 = a2[2];
    const float ep2 = b2[1], ep3 = b2[2];

    const double rms  = sqrt(tsq * (1.0 / S_LEN));
    const double m3   = (double)c3t * (1.0 / S_LEN);
    const double m4   = (double)c4t * (1.0 / S_LEN);
    const double skew = m3 / (var * stdv);
    const double kurt = m4 / (var * var);
    const float  amax = fmaxf(fabsf(tmax), fabsf(tmin));
    const double shape   = rms * (double)S_LEN / (double)tabs;
    const double impulse = (double)amax * (double)S_LEN / (double)tabs;
    const double sd1 = (double)ep3 - (double)ep0;
    const double sd2 = ((double)ep3 - (double)ep2) - ((double)ep1 - (double)ep0);
    const double var1 = ((double)s1qt - sd1 * sd1 * (1.0 / (S_LEN - 1))) * (1.0 / (S_LEN - 2));
    const double var2 = ((double)s2qt - sd2 * sd2 * (1.0 / (S_LEN - 2))) * (1.0 / (S_LEN - 3));

    float* o = out + (size_t)row * 15;
    o[0]  = (float)mean;
    o[1]  = tmax;
    o[2]  = tmin;
    o[3]  = tmax - tmin;
    o[4]  = (float)var;
    o[5]  = (float)rms;
    o[6]  = (float)skew;
    o[7]  = (float)kurt;
    o[8]  = (float)shape;
    o[9]  = (float)impulse;
    o[10] = outt;
    o[11] = zct * (1.0f / (2.0f * S_LEN));
    o[12] = (float)var;
    o[13] = (float)sqrt(var1 / var);
    o[14] = (float)sqrt(var2 / var1);
}

extern "C" void kernel_launch(void* const* d_in, const int* in_sizes, int n_in,
                              void* d_out, int out_size, void* d_ws, size_t ws_size,
                              hipStream_t stream) {
    (void)in_sizes; (void)n_in; (void)ws_size; (void)out_size;
    const float* in = (const float*)d_in[0];
    float* out = (float*)d_out;
    float* ws  = (float*)d_ws;
    health_pass1<<<8192, 256, 0, stream>>>(in, ws);
    health_finalize<<<64, 256, 0, stream>>>(ws, out);
}

// Round 5
// 36.692 us; speedup vs baseline: 1.4106x; 1.0873x over previous
//
#include <hip/hip_runtime.h>
#include <math.h>

// Health_State_Analysis: B=16384 rows, S=2560 fp32 -> 15 stats/row.
// k1: 2 waves/row, coalesced interleave, DPP reductions, packed moments,
//     lag-correlation (r1,r2) replacing diff streams, launch_bounds(256,6).
// k2: 16384 threads, f64 finalization incl. Hjorth algebra.

typedef float f32x2 __attribute__((ext_vector_type(2)));
typedef float f32x4 __attribute__((ext_vector_type(4)));

constexpr int S_LEN = 2560;
constexpr int NROWS = 16384;

#define DPP_ADD_F32(x, ctrl) do { \
    int t_ = __builtin_amdgcn_update_dpp(0, __float_as_int(x), ctrl, 0xf, 0xf, false); \
    x += __int_as_float(t_); } while (0)
#define DPP_MAX_F32(x, ctrl) do { \
    int t_ = __builtin_amdgcn_update_dpp(__float_as_int(x), __float_as_int(x), ctrl, 0xf, 0xf, false); \
    x = fmaxf(x, __int_as_float(t_)); } while (0)
#define DPP_MIN_F32(x, ctrl) do { \
    int t_ = __builtin_amdgcn_update_dpp(__float_as_int(x), __float_as_int(x), ctrl, 0xf, 0xf, false); \
    x = fminf(x, __int_as_float(t_)); } while (0)

__device__ __forceinline__ float wave_sum_f32(float x) {
    DPP_ADD_F32(x, 0x111); DPP_ADD_F32(x, 0x112); DPP_ADD_F32(x, 0x114);
    DPP_ADD_F32(x, 0x118); DPP_ADD_F32(x, 0x142); DPP_ADD_F32(x, 0x143);
    return x;  // lane 63
}
__device__ __forceinline__ float wave_max_f32(float x) {
    DPP_MAX_F32(x, 0x111); DPP_MAX_F32(x, 0x112); DPP_MAX_F32(x, 0x114);
    DPP_MAX_F32(x, 0x118); DPP_MAX_F32(x, 0x142); DPP_MAX_F32(x, 0x143);
    return x;
}
__device__ __forceinline__ float wave_min_f32(float x) {
    DPP_MIN_F32(x, 0x111); DPP_MIN_F32(x, 0x112); DPP_MIN_F32(x, 0x114);
    DPP_MIN_F32(x, 0x118); DPP_MIN_F32(x, 0x142); DPP_MIN_F32(x, 0x143);
    return x;
}
__device__ __forceinline__ double wave_sum_f64(double x) {
#define DPP_ADD_F64(ctrl) do { \
    long long b_ = __double_as_longlong(x); \
    int lo_ = __builtin_amdgcn_update_dpp(0, (int)(b_ & 0xffffffffLL), ctrl, 0xf, 0xf, false); \
    int hi_ = __builtin_amdgcn_update_dpp(0, (int)(b_ >> 32), ctrl, 0xf, 0xf, false); \
    x += __longlong_as_double(((long long)hi_ << 32) | (unsigned int)lo_); } while (0)
    DPP_ADD_F64(0x111); DPP_ADD_F64(0x112); DPP_ADD_F64(0x114);
    DPP_ADD_F64(0x118); DPP_ADD_F64(0x142); DPP_ADD_F64(0x143);
#undef DPP_ADD_F64
    return x;  // lane 63
}
__device__ __forceinline__ double readlane_f64(double x, int l) {
    long long b = __double_as_longlong(x);
    int lo = __builtin_amdgcn_readlane((int)(b & 0xffffffffLL), l);
    int hi = __builtin_amdgcn_readlane((int)(b >> 32), l);
    return __longlong_as_double(((long long)hi << 32) | (unsigned int)lo);
}

__global__ __launch_bounds__(256, 6)
void health_pass1(const float* __restrict__ in, float* __restrict__ ws) {
    __shared__ double Lsum[4], Lsq[4];
    __shared__ float  Lnb[2][2];

    const int lane = threadIdx.x & 63;
    const int wid  = threadIdx.x >> 6;   // 0..3
    const int hidx = wid & 1;            // half of row
    const int rsl  = wid >> 1;           // row slot in block
    const int row  = blockIdx.x * 2 + rsl;

    const f32x4* rp = reinterpret_cast<const f32x4*>(in)
                    + (size_t)row * (S_LEN / 4) + hidx * (1280 / 4) + lane;

    // ---- pass 1: coalesced load + raw sums (packed f32 -> f64 per lane) ----
    f32x4 X[5];
#pragma unroll
    for (int k = 0; k < 5; ++k) X[k] = rp[k * 64];

    f32x2 sp = {0.f, 0.f}, qp = {0.f, 0.f};
    float sabs = 0.f, vmax = -INFINITY, vmin = INFINITY;
#pragma unroll
    for (int k = 0; k < 5; ++k) {
        f32x2 lo = __builtin_shufflevector(X[k], X[k], 0, 1);
        f32x2 hi = __builtin_shufflevector(X[k], X[k], 2, 3);
        sp += lo + hi;
        qp = __builtin_elementwise_fma(lo, lo, qp);
        qp = __builtin_elementwise_fma(hi, hi, qp);
        sabs += (fabsf(X[k][0]) + fabsf(X[k][1])) + (fabsf(X[k][2]) + fabsf(X[k][3]));
        vmax = fmaxf(fmaxf(X[k][2], X[k][3]), fmaxf(fmaxf(X[k][0], X[k][1]), vmax));
        vmin = fminf(fminf(X[k][2], X[k][3]), fminf(fminf(X[k][0], X[k][1]), vmin));
    }

    const double sum_l = (double)sp.x + (double)sp.y;
    const double sq_l  = (double)qp.x + (double)qp.y;
    const double sum_u = readlane_f64(wave_sum_f64(sum_l), 63);
    const double sq_u  = readlane_f64(wave_sum_f64(sq_l), 63);

    // exchange sums with partner wave (other half of row)
    if (lane == 0) {
        Lsum[wid] = sum_u;  Lsq[wid] = sq_u;
        if (hidx == 1) { Lnb[rsl][0] = X[0][0]; Lnb[rsl][1] = X[0][1]; }
    }
    __syncthreads();
    const double tsum = Lsum[rsl * 2] + Lsum[rsl * 2 + 1];
    const double tsq  = Lsq[rsl * 2]  + Lsq[rsl * 2 + 1];

    const double mean = tsum * (1.0 / S_LEN);
    const double var  = (tsq - tsum * mean) * (1.0 / (S_LEN - 1));
    const double stdv = sqrt(var);
    const double thr  = 3.0 * stdv;
    const double bhi = mean + thr, blo = mean - thr;
    float bhi_f = (float)bhi;
    if ((double)bhi_f > bhi) bhi_f = __int_as_float(__float_as_int(bhi_f) - 1);  // RD (bhi>0)
    float blo_f = (float)blo;
    if ((double)blo_f < blo) blo_f = __int_as_float(__float_as_int(blo_f) - 1);  // RU (blo<0)

    // half0 tail splices x[1280],x[1281]; half1 tail pairs don't exist -> 0
    // (zero neighbor makes the invalid lag products vanish exactly)
    const float nbv0 = (hidx == 0) ? Lnb[rsl][0] : 0.f;
    const float nbv1 = (hidx == 0) ? Lnb[rsl][1] : 0.f;
    const float mf = (float)mean;
    const f32x2 nmf2 = {-mf, -mf};

    // ---- pass 2: moments (packed), outliers, zcr, lag correlations ----
    f32x2 c3p = {0.f, 0.f}, c4p = {0.f, 0.f};
    float r1 = 0.f, r2 = 0.f;
    int outc = 0, zcc = 0;
    const unsigned long long tail_ok = (hidx == 0) ? ~0ULL : 0x7FFFFFFFFFFFFFFFULL;

#pragma unroll
    for (int k = 0; k < 5; ++k) {
        const float x0 = X[k][0], x1 = X[k][1], x2v = X[k][2], x3 = X[k][3];
        const int kn = (k == 4) ? 0 : (k + 1);
        float v0 = (lane == 0) ? X[kn][0] : x0;
        float v1 = (lane == 0) ? X[kn][1] : x1;
        float n0 = __shfl(v0, (lane + 1) & 63);
        float n1 = __shfl(v1, (lane + 1) & 63);
        if (k == 4 && lane == 63) { n0 = nbv0; n1 = nbv1; }

        f32x2 lo = __builtin_shufflevector(X[k], X[k], 0, 1);
        f32x2 hi = __builtin_shufflevector(X[k], X[k], 2, 3);
        f32x2 cl = lo + nmf2, ch = hi + nmf2;
        f32x2 ql = cl * cl,  qh = ch * ch;
        c3p = __builtin_elementwise_fma(ql, cl, c3p);
        c3p = __builtin_elementwise_fma(qh, ch, c3p);
        c4p = __builtin_elementwise_fma(ql, ql, c4p);
        c4p = __builtin_elementwise_fma(qh, qh, c4p);

        outc += __popcll(__ballot(x0  > bhi_f || x0  < blo_f));
        outc += __popcll(__ballot(x1  > bhi_f || x1  < blo_f));
        outc += __popcll(__ballot(x2v > bhi_f || x2v < blo_f));
        outc += __popcll(__ballot(x3  > bhi_f || x3  < blo_f));

        const unsigned long long m0 = __ballot(x0  < 0.f);
        const unsigned long long m1 = __ballot(x1  < 0.f);
        const unsigned long long m2 = __ballot(x2v < 0.f);
        const unsigned long long m3 = __ballot(x3  < 0.f);
        const unsigned long long mn = __ballot(n0  < 0.f);
        zcc += __popcll(m0 ^ m1) + __popcll(m1 ^ m2) + __popcll(m2 ^ m3);
        zcc += __popcll((m3 ^ mn) & ((k == 4) ? tail_ok : ~0ULL));

        // lag-1 / lag-2 correlations (replace d1/d2 squared-diff streams)
        r1 = fmaf(x0, x1, fmaf(x1, x2v, fmaf(x2v, x3, fmaf(x3, n0, r1))));
        r2 = fmaf(x0, x2v, fmaf(x1, x3, fmaf(x2v, n0, fmaf(x3, n1, r2))));
    }

    float sabs_t = wave_sum_f32(sabs);
    float c3_t   = wave_sum_f32(c3p.x + c3p.y);
    float c4_t   = wave_sum_f32(c4p.x + c4p.y);
    float r1_t   = wave_sum_f32(r1);
    float r2_t   = wave_sum_f32(r2);
    float vmax_t = wave_max_f32(vmax);
    float vmin_t = wave_min_f32(vmin);

    float ep_a, ep_b;   // half0: x[0],x[1];  half1: x[2558],x[2559]
    if (hidx == 0) {
        ep_a = __int_as_float(__builtin_amdgcn_readlane(__float_as_int(X[0][0]), 0));
        ep_b = __int_as_float(__builtin_amdgcn_readlane(__float_as_int(X[0][1]), 0));
    } else {
        ep_a = X[4][2];  ep_b = X[4][3];   // valid on lane 63 (the storing lane)
    }

    if (lane == 63) {
        double2* Wd = reinterpret_cast<double2*>(ws);
        f32x4*   Wf = reinterpret_cast<f32x4*>(ws);
        double2 dsum; dsum.x = sum_u; dsum.y = sq_u;
        Wd[(size_t)hidx * NROWS + row] = dsum;                       // chunks 0,1
        const size_t b = (size_t)(2 + hidx * 3) * NROWS + row;       // chunks 2..7
        Wf[b]             = f32x4{sabs_t, vmax_t, vmin_t, c3_t};
        Wf[b + NROWS]     = f32x4{c4_t, r1_t, r2_t, (float)outc};
        Wf[b + 2 * NROWS] = f32x4{(float)zcc, ep_a, ep_b, 0.f};
    }
}

__global__ __launch_bounds__(256)
void health_finalize(const float* __restrict__ ws, float* __restrict__ out) {
    const int row = blockIdx.x * 256 + threadIdx.x;
    const double2* Wd = reinterpret_cast<const double2*>(ws);
    const f32x4*   Wf = reinterpret_cast<const f32x4*>(ws);

    const double2 s0 = Wd[row], s1 = Wd[NROWS + row];
    const f32x4 a0 = Wf[2 * NROWS + row], a1 = Wf[3 * NROWS + row], a2 = Wf[4 * NROWS + row];
    const f32x4 b0 = Wf[5 * NROWS + row], b1 = Wf[6 * NROWS + row], b2 = Wf[7 * NROWS + row];

    const double tsum = s0.x + s1.x;
    const double tsq  = s0.y + s1.y;
    const double mean = tsum * (1.0 / S_LEN);
    const double var  = (tsq - tsum * mean) * (1.0 / (S_LEN - 1));
    const double stdv = sqrt(var);

    const float tabs = a0[0] + b0[0];
    const float tmax = fmaxf(a0[1], b0[1]);
    const float tmin = fminf(a0[2], b0[2]);
    const float c3t  = a0[3] + b0[3];
    const float c4t  = a1[0] + b1[0];
    const double r1t = (double)a1[1] + (double)b1[1];
    const double r2t = (double)a1[2] + (double)b1[2];
    const float outt = a1[3] + b1[3];
    const float zct  = a2[0] + b2[0];
    const double e0 = (double)a2[1], e1 = (double)a2[2];   // x[0], x[1]
    const double e2 = (double)b2[1], e3 = (double)b2[2];   // x[2558], x[2559]

    const double rms  = sqrt(tsq * (1.0 / S_LEN));
    const double m3   = (double)c3t * (1.0 / S_LEN);
    const double m4   = (double)c4t * (1.0 / S_LEN);
    const double skew = m3 / (var * stdv);
    const double kurt = m4 / (var * var);
    const float  amax = fmaxf(fabsf(tmax), fabsf(tmin));
    const double shape   = rms * (double)S_LEN / (double)tabs;
    const double impulse = (double)amax * (double)S_LEN / (double)tabs;

    // Hjorth via lag-correlation algebra (exact identities over the f32 samples):
    // sum(d1^2) = 2Q - 2*r1 - x0^2 - x_{n-1}^2
    // sum(d2^2) = 6Q - 8*r1 + 2*r2 + 4*(x0*x1 + x_{n-2}*x_{n-1})
    //             - 5*x0^2 - x1^2 - x_{n-2}^2 - 5*x_{n-1}^2
    const double Q = tsq;
    const double s1q = 2.0 * Q - 2.0 * r1t - e0 * e0 - e3 * e3;
    const double s2q = 6.0 * Q - 8.0 * r1t + 2.0 * r2t
                     + 4.0 * (e0 * e1 + e2 * e3)
                     - 5.0 * e0 * e0 - e1 * e1 - e2 * e2 - 5.0 * e3 * e3;
    const double sd1 = e3 - e0;
    const double sd2 = (e3 - e2) - (e1 - e0);
    const double var1 = (s1q - sd1 * sd1 * (1.0 / (S_LEN - 1))) * (1.0 / (S_LEN - 2));
    const double var2 = (s2q - sd2 * sd2 * (1.0 / (S_LEN - 2))) * (1.0 / (S_LEN - 3));

    float* o = out + (size_t)row * 15;
    o[0]  = (float)mean;
    o[1]  = tmax;
    o[2]  = tmin;
    o[3]  = tmax - tmin;
    o[4]  = (float)var;
    o[5]  = (float)rms;
    o[6]  = (float)skew;
    o[7]  = (float)kurt;
    o[8]  = (float)shape;
    o[9]  = (float)impulse;
    o[10] = outt;
    o[11] = zct * (1.0f / (2.0f * S_LEN));
    o[12] = (float)var;
    o[13] = (float)sqrt(var1 / var);
    o[14] = (float)sqrt(var2 / var1);
}

extern "C" void kernel_launch(void* const* d_in, const int* in_sizes, int n_in,
                              void* d_out, int out_size, void* d_ws, size_t ws_size,
                              hipStream_t stream) {
    (void)in_sizes; (void)n_in; (void)ws_size; (void)out_size;
    const float* in = (const float*)d_in[0];
    float* out = (float*)d_out;
    float* ws  = (float*)d_ws;
    health_pass1<<<8192, 256, 0, stream>>>(in, ws);
    health_finalize<<<64, 256, 0, stream>>>(ws, out);
}